// Round 6
// baseline (483.487 us; speedup 1.0000x reference)
//
#include <hip/hip_runtime.h>
#include <math.h>

typedef unsigned short u16;
typedef __attribute__((ext_vector_type(4))) float f32x4;
typedef __attribute__((ext_vector_type(8))) short s16x8;
typedef __attribute__((ext_vector_type(8))) unsigned short u16x8;
typedef __attribute__((ext_vector_type(4))) unsigned short u16x4;

__device__ __forceinline__ float bf2f(u16 v) {
    union { unsigned u; float f; } c; c.u = ((unsigned)v) << 16; return c.f;
}
__device__ __forceinline__ u16 f2bf(float f) {
    union { float f; unsigned u; } c; c.f = f;
    unsigned x = c.u;
    unsigned r = (x + 0x7fffu + ((x >> 16) & 1u)) >> 16;  // RNE
    return (u16)r;
}

// async HBM -> LDS, 16 B per lane. LDS dest is wave-uniform base + lane*16.
__device__ __forceinline__ void async_copy16(const u16* g, u16* l) {
    __builtin_amdgcn_global_load_lds(
        (const __attribute__((address_space(1))) unsigned int*)g,
        (__attribute__((address_space(3))) unsigned int*)l, 16, 0, 0);
}

// ---------------- fp32 -> bf16 weight conversion (both weights, one launch) --
__global__ __launch_bounds__(256)
void cvt_kernel(const float* __restrict__ in_a, u16* __restrict__ out_a, int n4a,
                const float* __restrict__ in_b, u16* __restrict__ out_b, int n4b) {
    int i = blockIdx.x * 256 + threadIdx.x;
    const float* in; u16* out; int k;
    if (i < n4a) { in = in_a; out = out_a; k = i; }
    else if (i < n4a + n4b) { in = in_b; out = out_b; k = i - n4a; }
    else return;
    float4 v = reinterpret_cast<const float4*>(in)[k];
    u16x4 o;
    o[0] = f2bf(v.x); o[1] = f2bf(v.y); o[2] = f2bf(v.z); o[3] = f2bf(v.w);
    reinterpret_cast<u16x4*>(out)[k] = o;
}

// ---------------- LayerNorm: x fp32 (8192 x 1024) -> u bf16 ----------------
__global__ __launch_bounds__(256)
void ln_kernel(const float* __restrict__ x, const float* __restrict__ w,
               const float* __restrict__ b, u16* __restrict__ u) {
    int row = blockIdx.x, t = threadIdx.x;
    const float* xr = x + (size_t)row * 1024;
    float4 xv = *reinterpret_cast<const float4*>(xr + t * 4);
    float f[4] = {xv.x, xv.y, xv.z, xv.w};
    float s = 0.f, sq = 0.f;
    #pragma unroll
    for (int i = 0; i < 4; i++) { s += f[i]; sq += f[i] * f[i]; }
    #pragma unroll
    for (int o = 32; o; o >>= 1) { s += __shfl_down(s, o); sq += __shfl_down(sq, o); }
    __shared__ float rs[4], rq[4];
    int lane = t & 63, wv = t >> 6;
    if (!lane) { rs[wv] = s; rq[wv] = sq; }
    __syncthreads();
    s = rs[0] + rs[1] + rs[2] + rs[3];
    sq = rq[0] + rq[1] + rq[2] + rq[3];
    float mu = s * (1.f / 1024.f);
    float var = sq * (1.f / 1024.f) - mu * mu;
    float rstd = rsqrtf(var + 1e-5f);
    float4 wv4 = *reinterpret_cast<const float4*>(w + t * 4);
    float4 bv4 = *reinterpret_cast<const float4*>(b + t * 4);
    float wf[4] = {wv4.x, wv4.y, wv4.z, wv4.w};
    float bf[4] = {bv4.x, bv4.y, bv4.z, bv4.w};
    u16x4 o4;
    #pragma unroll
    for (int i = 0; i < 4; i++)
        o4[i] = f2bf((f[i] - mu) * rstd * wf[i] + bf[i]);
    *reinterpret_cast<u16x4*>(u + (size_t)row * 1024 + t * 4) = o4;
}

// ---------------- GEMM1: zxbcdt = u @ W_in^T, split epilogue ----------------
// m97 staging + BK=64 (two 32-wide LDS panels per barrier pair).
__global__ __launch_bounds__(256)
void gemm_in_kernel(const u16* __restrict__ A, const u16* __restrict__ W,
                    u16* __restrict__ zbuf, u16* __restrict__ xbc,
                    float* __restrict__ dtsp, const float* __restrict__ dt_bias,
                    int M, int N, int K) {
    __shared__ __align__(16) u16 As[2 * 128 * 32];
    __shared__ __align__(16) u16 Bs[2 * 128 * 32];
    int t = threadIdx.x;
    int m0 = blockIdx.x * 128, n0 = blockIdx.y * 128;
    int wave = t >> 6, lane = t & 63;
    int wm = (wave >> 1) * 64, wn = (wave & 1) * 64;
    int lm = lane & 15, lq = lane >> 4;
    int srow = lane >> 2, scol = (lane & 3) * 8;   // 4 lanes cover one 32-col row
    f32x4 acc[4][4];
    #pragma unroll
    for (int i = 0; i < 4; i++)
        #pragma unroll
        for (int j = 0; j < 4; j++) acc[i][j] = (f32x4){0.f, 0.f, 0.f, 0.f};

    for (int k0 = 0; k0 < K; k0 += 64) {
        #pragma unroll
        for (int p = 0; p < 2; p++) {
            #pragma unroll
            for (int s = 0; s < 2; s++) {
                int ch = s * 4 + wave;               // 8 chunks of 16 rows / panel
                int row = ch * 16 + srow;
                async_copy16(A + (size_t)(m0 + row) * K + k0 + p * 32 + scol,
                             &As[p * 4096 + ch * 512 + lane * 8]);
                int rn = n0 + row;
                if (rn < N)
                    async_copy16(W + (size_t)rn * K + k0 + p * 32 + scol,
                                 &Bs[p * 4096 + ch * 512 + lane * 8]);
            }
        }
        __syncthreads();
        #pragma unroll
        for (int p = 0; p < 2; p++) {
            s16x8 af[4], bfr[4];
            #pragma unroll
            for (int i = 0; i < 4; i++)
                af[i] = *reinterpret_cast<const s16x8*>(&As[p * 4096 + (wm + i * 16 + lm) * 32 + lq * 8]);
            #pragma unroll
            for (int j = 0; j < 4; j++)
                bfr[j] = *reinterpret_cast<const s16x8*>(&Bs[p * 4096 + (wn + j * 16 + lm) * 32 + lq * 8]);
            #pragma unroll
            for (int i = 0; i < 4; i++)
                #pragma unroll
                for (int j = 0; j < 4; j++)
                    acc[i][j] = __builtin_amdgcn_mfma_f32_16x16x32_bf16(af[i], bfr[j], acc[i][j], 0, 0, 0);
        }
        __syncthreads();
    }
    #pragma unroll
    for (int i = 0; i < 4; i++) {
        #pragma unroll
        for (int j = 0; j < 4; j++) {
            int col = n0 + wn + j * 16 + lm;
            if (col < N) {
                #pragma unroll
                for (int r = 0; r < 4; r++) {
                    int row = m0 + wm + i * 16 + lq * 4 + r;
                    float v = acc[i][j][r];
                    if (col < 2048) {
                        zbuf[(size_t)row * 2048 + col] = f2bf(v);
                    } else if (col < 4224) {
                        xbc[(size_t)row * 2176 + (col - 2048)] = f2bf(v);
                    } else {
                        float tt = v + dt_bias[col - 4224];
                        float sp = (tt > 20.f) ? tt : log1pf(expf(tt));
                        dtsp[(size_t)row * 32 + (col - 4224)] = sp;
                    }
                }
            }
        }
    }
}

// ---------------- GEMM2: out = yfin @ W_out^T + x (fp32 out) ----------------
__global__ __launch_bounds__(256)
void gemm_out_kernel(const u16* __restrict__ A, const u16* __restrict__ W,
                     float* __restrict__ C, const float* __restrict__ resid,
                     int M, int N, int K) {
    __shared__ __align__(16) u16 As[2 * 128 * 32];
    __shared__ __align__(16) u16 Bs[2 * 128 * 32];
    int t = threadIdx.x;
    int m0 = blockIdx.x * 128, n0 = blockIdx.y * 128;
    int wave = t >> 6, lane = t & 63;
    int wm = (wave >> 1) * 64, wn = (wave & 1) * 64;
    int lm = lane & 15, lq = lane >> 4;
    int srow = lane >> 2, scol = (lane & 3) * 8;
    f32x4 acc[4][4];
    #pragma unroll
    for (int i = 0; i < 4; i++)
        #pragma unroll
        for (int j = 0; j < 4; j++) acc[i][j] = (f32x4){0.f, 0.f, 0.f, 0.f};
    for (int k0 = 0; k0 < K; k0 += 64) {
        #pragma unroll
        for (int p = 0; p < 2; p++) {
            #pragma unroll
            for (int s = 0; s < 2; s++) {
                int ch = s * 4 + wave;
                int row = ch * 16 + srow;
                async_copy16(A + (size_t)(m0 + row) * K + k0 + p * 32 + scol,
                             &As[p * 4096 + ch * 512 + lane * 8]);
                async_copy16(W + (size_t)(n0 + row) * K + k0 + p * 32 + scol,
                             &Bs[p * 4096 + ch * 512 + lane * 8]);
            }
        }
        __syncthreads();
        #pragma unroll
        for (int p = 0; p < 2; p++) {
            s16x8 af[4], bfr[4];
            #pragma unroll
            for (int i = 0; i < 4; i++)
                af[i] = *reinterpret_cast<const s16x8*>(&As[p * 4096 + (wm + i * 16 + lm) * 32 + lq * 8]);
            #pragma unroll
            for (int j = 0; j < 4; j++)
                bfr[j] = *reinterpret_cast<const s16x8*>(&Bs[p * 4096 + (wn + j * 16 + lm) * 32 + lq * 8]);
            #pragma unroll
            for (int i = 0; i < 4; i++)
                #pragma unroll
                for (int j = 0; j < 4; j++)
                    acc[i][j] = __builtin_amdgcn_mfma_f32_16x16x32_bf16(af[i], bfr[j], acc[i][j], 0, 0, 0);
        }
        __syncthreads();
    }
    #pragma unroll
    for (int i = 0; i < 4; i++)
        #pragma unroll
        for (int j = 0; j < 4; j++) {
            int col = n0 + wn + j * 16 + lm;
            #pragma unroll
            for (int r = 0; r < 4; r++) {
                int row = m0 + wm + i * 16 + lq * 4 + r;
                size_t off = (size_t)row * N + col;
                C[off] = acc[i][j][r] + resid[off];
            }
        }
}

// ---------------- depthwise causal conv (width 4) + bias + SiLU --------------
// 8 channels per thread, u16x8 vector loads/stores.
__global__ __launch_bounds__(256)
void conv_kernel(const u16* __restrict__ xbc, const float* __restrict__ cw,
                 const float* __restrict__ cb, u16* __restrict__ xact) {
    int idx = blockIdx.x * 256 + threadIdx.x;
    if (idx >= 8192 * 272) return;
    int c0 = (idx % 272) * 8;
    int bl = idx / 272;
    int l = bl & 4095, b = bl >> 12;
    float acc[8];
    #pragma unroll
    for (int i = 0; i < 8; i++) acc[i] = cb[c0 + i];
    #pragma unroll
    for (int k = 0; k < 4; k++) {
        int lk = l - 3 + k;
        if (lk >= 0) {
            u16x8 v = *reinterpret_cast<const u16x8*>(
                xbc + (size_t)(b * 4096 + lk) * 2176 + c0);
            #pragma unroll
            for (int i = 0; i < 8; i++)
                acc[i] += cw[(c0 + i) * 4 + k] * bf2f(v[i]);
        }
    }
    u16x8 o;
    #pragma unroll
    for (int i = 0; i < 8; i++) {
        float s = acc[i] / (1.f + expf(-acc[i]));
        o[i] = f2bf(s);
    }
    *reinterpret_cast<u16x8*>(xact + (size_t)bl * 2176 + c0) = o;
}

// ====== chunked SSD scan: Q=64 chunks, units = (b,h,c) = 2*32*64 = 4096 ======
#define TS 72
__device__ __forceinline__ void mfma_quad(const u16* Pa, const u16* Qb,
                                          int mh, int nh, int lm, int lq,
                                          f32x4 acc[2][2]) {
    #pragma unroll
    for (int ks = 0; ks < 2; ks++) {
        s16x8 a[2], b[2];
        #pragma unroll
        for (int ti = 0; ti < 2; ti++)
            a[ti] = *reinterpret_cast<const s16x8*>(&Pa[(mh * 32 + ti * 16 + lm) * TS + ks * 32 + lq * 8]);
        #pragma unroll
        for (int tj = 0; tj < 2; tj++)
            b[tj] = *reinterpret_cast<const s16x8*>(&Qb[(nh * 32 + tj * 16 + lm) * TS + ks * 32 + lq * 8]);
        #pragma unroll
        for (int ti = 0; ti < 2; ti++)
            #pragma unroll
            for (int tj = 0; tj < 2; tj++)
                acc[ti][tj] = __builtin_amdgcn_mfma_f32_16x16x32_bf16(a[ti], b[tj], acc[ti][tj], 0, 0, 0);
    }
}

// Phase A: per unit, cumsum s_j, w_j = exp(s63-s_j)*dt_j; dH[p,n] = sum_j w_j x[j,p] B[j,n]
__global__ __launch_bounds__(256)
void chunk_dh_kernel(const u16* __restrict__ xact, const float* __restrict__ dtsp,
                     const float* __restrict__ A_log,
                     float* __restrict__ ssum, u16* __restrict__ dH) {
    int blk = blockIdx.x;
    int c = blk & 63, h = (blk >> 6) & 31, b = blk >> 11;
    __shared__ __align__(16) u16 Xw[64 * TS];
    __shared__ __align__(16) u16 Bt[64 * TS];
    __shared__ float sW[64];
    int t = threadIdx.x;
    int row0 = b * 4096 + c * 64;
    if (t < 64) {
        float dtv = dtsp[(size_t)(row0 + t) * 32 + h];
        float Ah = -__expf(A_log[h]);
        float s = dtv * Ah;
        #pragma unroll
        for (int o = 1; o < 64; o <<= 1) {
            float up = __shfl_up(s, o);
            if (t >= o) s += up;
        }
        float slast = __shfl(s, 63);
        sW[t] = __expf(slast - s) * dtv;
        ssum[(size_t)blk * 64 + t] = s;
    }
    __syncthreads();
    int j = t & 63, cg = (t >> 6) * 16;
    {
        float wj = sW[j];
        const u16* xr = xact + (size_t)(row0 + j) * 2176 + h * 64 + cg;
        u16x8 v0 = *reinterpret_cast<const u16x8*>(xr);
        u16x8 v1 = *reinterpret_cast<const u16x8*>(xr + 8);
        #pragma unroll
        for (int i = 0; i < 8; i++) Xw[(cg + i) * TS + j] = f2bf(bf2f(v0[i]) * wj);
        #pragma unroll
        for (int i = 0; i < 8; i++) Xw[(cg + 8 + i) * TS + j] = f2bf(bf2f(v1[i]) * wj);
        const u16* br = xact + (size_t)(row0 + j) * 2176 + 2048 + cg;
        u16x8 w0 = *reinterpret_cast<const u16x8*>(br);
        u16x8 w1 = *reinterpret_cast<const u16x8*>(br + 8);
        #pragma unroll
        for (int i = 0; i < 8; i++) Bt[(cg + i) * TS + j] = w0[i];
        #pragma unroll
        for (int i = 0; i < 8; i++) Bt[(cg + 8 + i) * TS + j] = w1[i];
    }
    __syncthreads();
    int wave = t >> 6, lane = t & 63, lm = lane & 15, lq = lane >> 4;
    int mh = wave >> 1, nh = wave & 1;
    f32x4 acc[2][2];
    #pragma unroll
    for (int i = 0; i < 2; i++)
        #pragma unroll
        for (int jj = 0; jj < 2; jj++) acc[i][jj] = (f32x4){0.f, 0.f, 0.f, 0.f};
    mfma_quad(Xw, Bt, mh, nh, lm, lq, acc);
    u16* out = dH + (size_t)blk * 4096;
    #pragma unroll
    for (int ti = 0; ti < 2; ti++)
        #pragma unroll
        for (int tj = 0; tj < 2; tj++)
            #pragma unroll
            for (int r = 0; r < 4; r++) {
                int p = mh * 32 + ti * 16 + lq * 4 + r;
                int n = nh * 32 + tj * 16 + lm;
                out[p * 64 + n] = f2bf(acc[ti][tj][r]);
            }
}

// Phase B: inter-chunk recurrence. grid (64 bh, 8 col-groups), 128 threads, 4 states each.
__global__ __launch_bounds__(128)
void chunk_scan_kernel(const u16* __restrict__ dH, const float* __restrict__ ssum,
                       u16* __restrict__ Hst) {
    int bh = blockIdx.x, g = blockIdx.y, t = threadIdx.x;
    int idx = g * 512 + t * 4;
    float H[4] = {0.f, 0.f, 0.f, 0.f};
    for (int c = 0; c < 64; c++) {
        size_t base = ((size_t)bh * 64 + c) * 4096 + idx;
        float lam = __expf(ssum[((size_t)bh * 64 + c) * 64 + 63]);
        u16x4 dh = *reinterpret_cast<const u16x4*>(dH + base);
        u16x4 hv;
        #pragma unroll
        for (int i = 0; i < 4; i++) hv[i] = f2bf(H[i]);
        *reinterpret_cast<u16x4*>(Hst + base) = hv;
        #pragma unroll
        for (int i = 0; i < 4; i++) H[i] = H[i] * lam + bf2f(dh[i]);
    }
}

// Phase C: per unit: G=C.B^T -> M (masked/weighted) ; Y = M@X + exp(s_i)*(C@H^T) + D*x
__global__ __launch_bounds__(256)
void chunk_out_kernel(const u16* __restrict__ xact, const float* __restrict__ dtsp,
                      const float* __restrict__ ssum, const u16* __restrict__ Hst,
                      const float* __restrict__ Dp, u16* __restrict__ yraw) {
    int blk = blockIdx.x;
    int c = blk & 63, h = (blk >> 6) & 31, b = blk >> 11;
    __shared__ __align__(16) u16 Ct[64 * TS];
    __shared__ __align__(16) u16 BM[64 * TS];
    __shared__ __align__(16) u16 Xt[64 * TS];
    __shared__ __align__(16) u16 Hs[64 * TS];
    __shared__ float sS[64], sDt[64], sE[64];
    int t = threadIdx.x;
    int row0 = b * 4096 + c * 64;
    if (t < 64) {
        float dtv = dtsp[(size_t)(row0 + t) * 32 + h];
        float s = ssum[(size_t)blk * 64 + t];
        sS[t] = s; sDt[t] = dtv; sE[t] = __expf(s);
    }
    int r2 = t >> 2, cg2 = (t & 3) * 16;
    {
        const u16* cr = xact + (size_t)(row0 + r2) * 2176 + 2112 + cg2;
        *reinterpret_cast<u16x8*>(&Ct[r2 * TS + cg2]) = *reinterpret_cast<const u16x8*>(cr);
        *reinterpret_cast<u16x8*>(&Ct[r2 * TS + cg2 + 8]) = *reinterpret_cast<const u16x8*>(cr + 8);
        const u16* br = xact + (size_t)(row0 + r2) * 2176 + 2048 + cg2;
        *reinterpret_cast<u16x8*>(&BM[r2 * TS + cg2]) = *reinterpret_cast<const u16x8*>(br);
        *reinterpret_cast<u16x8*>(&BM[r2 * TS + cg2 + 8]) = *reinterpret_cast<const u16x8*>(br + 8);
        const u16* hr = Hst + (size_t)blk * 4096 + r2 * 64 + cg2;
        *reinterpret_cast<u16x8*>(&Hs[r2 * TS + cg2]) = *reinterpret_cast<const u16x8*>(hr);
        *reinterpret_cast<u16x8*>(&Hs[r2 * TS + cg2 + 8]) = *reinterpret_cast<const u16x8*>(hr + 8);
    }
    int j = t & 63, cg = (t >> 6) * 16;
    {
        const u16* xr = xact + (size_t)(row0 + j) * 2176 + h * 64 + cg;
        u16x8 v0 = *reinterpret_cast<const u16x8*>(xr);
        u16x8 v1 = *reinterpret_cast<const u16x8*>(xr + 8);
        #pragma unroll
        for (int i = 0; i < 8; i++) Xt[(cg + i) * TS + j] = v0[i];
        #pragma unroll
        for (int i = 0; i < 8; i++) Xt[(cg + 8 + i) * TS + j] = v1[i];
    }
    __syncthreads();
    int wave = t >> 6, lane = t & 63, lm = lane & 15, lq = lane >> 4;
    int mh = wave >> 1, nh = wave & 1;
    f32x4 g1[2][2], y2[2][2], y3[2][2];
    #pragma unroll
    for (int i = 0; i < 2; i++)
        #pragma unroll
        for (int jj = 0; jj < 2; jj++) {
            g1[i][jj] = (f32x4){0.f, 0.f, 0.f, 0.f};
            y2[i][jj] = (f32x4){0.f, 0.f, 0.f, 0.f};
            y3[i][jj] = (f32x4){0.f, 0.f, 0.f, 0.f};
        }
    mfma_quad(Ct, BM, mh, nh, lm, lq, g1);
    __syncthreads();
    #pragma unroll
    for (int ti = 0; ti < 2; ti++)
        #pragma unroll
        for (int tj = 0; tj < 2; tj++) {
            int j_ = nh * 32 + tj * 16 + lm;
            float sj = sS[j_], dtj = sDt[j_];
            #pragma unroll
            for (int r = 0; r < 4; r++) {
                int ii = mh * 32 + ti * 16 + lq * 4 + r;
                float v = g1[ti][tj][r] * __expf(sS[ii] - sj) * dtj;
                v = (j_ <= ii) ? v : 0.f;
                BM[ii * TS + j_] = f2bf(v);
            }
        }
    __syncthreads();
    mfma_quad(BM, Xt, mh, nh, lm, lq, y2);
    mfma_quad(Ct, Hs, mh, nh, lm, lq, y3);
    float Dh = Dp[h];
    #pragma unroll
    for (int ti = 0; ti < 2; ti++)
        #pragma unroll
        for (int tj = 0; tj < 2; tj++)
            #pragma unroll
            for (int r = 0; r < 4; r++) {
                int ii = mh * 32 + ti * 16 + lq * 4 + r;
                int p = nh * 32 + tj * 16 + lm;
                float xv = bf2f(Xt[p * TS + ii]);
                float y = y2[ti][tj][r] + sE[ii] * y3[ti][tj][r] + Dh * xv;
                yraw[(size_t)(row0 + ii) * 2048 + h * 64 + p] = f2bf(y);
            }
}

// ---------------- gate (y * silu(z)) + RMSNorm * norm_w ----------------
__global__ __launch_bounds__(256)
void gate_kernel(const u16* __restrict__ yraw, const u16* __restrict__ zbuf,
                 const float* __restrict__ nw, u16* __restrict__ yfin) {
    int row = blockIdx.x, t = threadIdx.x;
    u16x8 yv = *reinterpret_cast<const u16x8*>(yraw + (size_t)row * 2048 + t * 8);
    u16x8 zv = *reinterpret_cast<const u16x8*>(zbuf + (size_t)row * 2048 + t * 8);
    float g[8]; float sq = 0.f;
    #pragma unroll
    for (int i = 0; i < 8; i++) {
        float z = bf2f(zv[i]);
        float gg = bf2f(yv[i]) * (z / (1.f + expf(-z)));
        g[i] = gg; sq += gg * gg;
    }
    #pragma unroll
    for (int o = 32; o; o >>= 1) sq += __shfl_down(sq, o);
    __shared__ float rq[4];
    int lane = t & 63, wv = t >> 6;
    if (!lane) rq[wv] = sq;
    __syncthreads();
    sq = rq[0] + rq[1] + rq[2] + rq[3];
    float scale = rsqrtf(sq * (1.f / 2048.f) + 1e-5f);
    float4 n0 = *reinterpret_cast<const float4*>(nw + t * 8);
    float4 n1 = *reinterpret_cast<const float4*>(nw + t * 8 + 4);
    float nf[8] = {n0.x, n0.y, n0.z, n0.w, n1.x, n1.y, n1.z, n1.w};
    u16x8 o8;
    #pragma unroll
    for (int i = 0; i < 8; i++) o8[i] = f2bf(g[i] * scale * nf[i]);
    *reinterpret_cast<u16x8*>(yfin + (size_t)row * 2048 + t * 8) = o8;
}

extern "C" void kernel_launch(void* const* d_in, const int* in_sizes, int n_in,
                              void* d_out, int out_size, void* d_ws, size_t ws_size,
                              hipStream_t stream) {
    const float* x       = (const float*)d_in[0];
    const float* ln_w    = (const float*)d_in[1];
    const float* ln_b    = (const float*)d_in[2];
    const float* W_in    = (const float*)d_in[3];
    const float* conv_w  = (const float*)d_in[4];
    const float* conv_b  = (const float*)d_in[5];
    const float* dt_bias = (const float*)d_in[6];
    const float* A_log   = (const float*)d_in[7];
    const float* Dp      = (const float*)d_in[8];
    const float* norm_w  = (const float*)d_in[9];
    const float* W_out   = (const float*)d_in[10];
    float* out = (float*)d_out;

    char* ws = (char*)d_ws;
    u16*  zbuf    = (u16*)(ws + 0);               // 33,554,432  [gemm1 -> gate]
    u16*  xbc     = (u16*)(ws + 33554432);        // 35,651,584  [gemm1 -> conv]
    u16*  Hst     = (u16*)(ws + 33554432);        // 33,554,432  [phaseB -> phaseC] overlays xbc
    u16*  xact    = (u16*)(ws + 69206016);        // 35,651,584  [conv -> phaseC]
    u16*  yfin    = xact;                         // [gate -> gemm2] overlays xact
    u16*  u_buf   = (u16*)(ws + 104857600);       // 16,777,216  [ln -> gemm1]
    float* ssum   = (float*)(ws + 104857600);     //  1,048,576  [phaseA -> phaseC] overlays u_buf
    float* dtsp   = (float*)(ws + 121634816);     //  1,048,576  [gemm1 -> phaseC]
    u16*  dH      = (u16*)(ws + 122683392);       // 33,554,432  [phaseA -> phaseB]
    u16*  yraw    = (u16*)(ws + 122683392);       // [phaseC -> gate] overlays dH
    u16*  w_in_bf = (u16*)(ws + 156237824);       //  8,716,288
    u16*  w_out_bf= (u16*)(ws + 164954112);       //  4,194,304

    cvt_kernel<<<(1089536 + 524288 + 255) / 256, 256, 0, stream>>>(
        W_in, w_in_bf, 1089536, W_out, w_out_bf, 524288);

    ln_kernel<<<8192, 256, 0, stream>>>(x, ln_w, ln_b, u_buf);

    dim3 g1(64, 34);
    gemm_in_kernel<<<g1, 256, 0, stream>>>(u_buf, w_in_bf, zbuf, xbc, dtsp, dt_bias,
                                           8192, 4256, 1024);

    conv_kernel<<<(8192 * 272) / 256, 256, 0, stream>>>(xbc, conv_w, conv_b, xact);

    chunk_dh_kernel<<<4096, 256, 0, stream>>>(xact, dtsp, A_log, ssum, dH);
    chunk_scan_kernel<<<dim3(64, 8), 128, 0, stream>>>(dH, ssum, Hst);
    chunk_out_kernel<<<4096, 256, 0, stream>>>(xact, dtsp, ssum, Hst, Dp, yraw);

    gate_kernel<<<8192, 256, 0, stream>>>(yraw, zbuf, norm_w, yfin);

    dim3 g2(64, 8);
    gemm_out_kernel<<<g2, 256, 0, stream>>>(yfin, w_out_bf, out, x, 8192, 1024, 2048);
}

// Round 7
// 384.392 us; speedup vs baseline: 1.2578x; 1.2578x over previous
//
#include <hip/hip_runtime.h>
#include <math.h>

typedef unsigned short u16;
typedef __attribute__((ext_vector_type(4))) float f32x4;
typedef __attribute__((ext_vector_type(8))) short s16x8;
typedef __attribute__((ext_vector_type(8))) unsigned short u16x8;
typedef __attribute__((ext_vector_type(4))) unsigned short u16x4;

__device__ __forceinline__ float bf2f(u16 v) {
    union { unsigned u; float f; } c; c.u = ((unsigned)v) << 16; return c.f;
}
__device__ __forceinline__ u16 f2bf(float f) {
    union { float f; unsigned u; } c; c.f = f;
    unsigned x = c.u;
    unsigned r = (x + 0x7fffu + ((x >> 16) & 1u)) >> 16;  // RNE
    return (u16)r;
}

// async HBM -> LDS, 16 B per lane. LDS dest is wave-uniform base + lane*16.
__device__ __forceinline__ void async_copy16(const u16* g, u16* l) {
    __builtin_amdgcn_global_load_lds(
        (const __attribute__((address_space(1))) unsigned int*)g,
        (__attribute__((address_space(3))) unsigned int*)l, 16, 0, 0);
}

// ---------------- fp32 -> bf16 weight conversion (both weights, one launch) --
__global__ __launch_bounds__(256)
void cvt_kernel(const float* __restrict__ in_a, u16* __restrict__ out_a, int n4a,
                const float* __restrict__ in_b, u16* __restrict__ out_b, int n4b) {
    int i = blockIdx.x * 256 + threadIdx.x;
    const float* in; u16* out; int k;
    if (i < n4a) { in = in_a; out = out_a; k = i; }
    else if (i < n4a + n4b) { in = in_b; out = out_b; k = i - n4a; }
    else return;
    float4 v = reinterpret_cast<const float4*>(in)[k];
    u16x4 o;
    o[0] = f2bf(v.x); o[1] = f2bf(v.y); o[2] = f2bf(v.z); o[3] = f2bf(v.w);
    reinterpret_cast<u16x4*>(out)[k] = o;
}

// ---------------- LayerNorm: x fp32 (8192 x 1024) -> u bf16 ----------------
__global__ __launch_bounds__(256)
void ln_kernel(const float* __restrict__ x, const float* __restrict__ w,
               const float* __restrict__ b, u16* __restrict__ u) {
    int row = blockIdx.x, t = threadIdx.x;
    const float* xr = x + (size_t)row * 1024;
    float4 xv = *reinterpret_cast<const float4*>(xr + t * 4);
    float f[4] = {xv.x, xv.y, xv.z, xv.w};
    float s = 0.f, sq = 0.f;
    #pragma unroll
    for (int i = 0; i < 4; i++) { s += f[i]; sq += f[i] * f[i]; }
    #pragma unroll
    for (int o = 32; o; o >>= 1) { s += __shfl_down(s, o); sq += __shfl_down(sq, o); }
    __shared__ float rs[4], rq[4];
    int lane = t & 63, wv = t >> 6;
    if (!lane) { rs[wv] = s; rq[wv] = sq; }
    __syncthreads();
    s = rs[0] + rs[1] + rs[2] + rs[3];
    sq = rq[0] + rq[1] + rq[2] + rq[3];
    float mu = s * (1.f / 1024.f);
    float var = sq * (1.f / 1024.f) - mu * mu;
    float rstd = rsqrtf(var + 1e-5f);
    float4 wv4 = *reinterpret_cast<const float4*>(w + t * 4);
    float4 bv4 = *reinterpret_cast<const float4*>(b + t * 4);
    float wf[4] = {wv4.x, wv4.y, wv4.z, wv4.w};
    float bf[4] = {bv4.x, bv4.y, bv4.z, bv4.w};
    u16x4 o4;
    #pragma unroll
    for (int i = 0; i < 4; i++)
        o4[i] = f2bf((f[i] - mu) * rstd * wf[i] + bf[i]);
    *reinterpret_cast<u16x4*>(u + (size_t)row * 1024 + t * 4) = o4;
}

// ---------------- GEMM1: zxbcdt = u @ W_in^T, split epilogue ----------------
// m97 structure (round-5 measured 130us): BK=32, global_load_lds 16B staging.
__global__ __launch_bounds__(256)
void gemm_in_kernel(const u16* __restrict__ A, const u16* __restrict__ W,
                    u16* __restrict__ zbuf, u16* __restrict__ xbc,
                    float* __restrict__ dtsp, const float* __restrict__ dt_bias,
                    int M, int N, int K) {
    __shared__ __align__(16) u16 As[128 * 32];
    __shared__ __align__(16) u16 Bs[128 * 32];
    int t = threadIdx.x;
    int m0 = blockIdx.x * 128, n0 = blockIdx.y * 128;
    int wave = t >> 6, lane = t & 63;
    int wm = (wave >> 1) * 64, wn = (wave & 1) * 64;
    int lm = lane & 15, lq = lane >> 4;
    int srow = lane >> 2, scol = (lane & 3) * 8;   // 4 lanes cover one 32-col row
    f32x4 acc[4][4];
    #pragma unroll
    for (int i = 0; i < 4; i++)
        #pragma unroll
        for (int j = 0; j < 4; j++) acc[i][j] = (f32x4){0.f, 0.f, 0.f, 0.f};

    for (int k0 = 0; k0 < K; k0 += 32) {
        #pragma unroll
        for (int s = 0; s < 2; s++) {
            int ch = s * 4 + wave;               // 8 chunks of 16 rows
            int row = ch * 16 + srow;
            async_copy16(A + (size_t)(m0 + row) * K + k0 + scol, &As[ch * 512 + lane * 8]);
            int rn = n0 + row;
            if (rn < N)
                async_copy16(W + (size_t)rn * K + k0 + scol, &Bs[ch * 512 + lane * 8]);
        }
        __syncthreads();
        s16x8 af[4], bfr[4];
        #pragma unroll
        for (int i = 0; i < 4; i++)
            af[i] = *reinterpret_cast<const s16x8*>(&As[(wm + i * 16 + lm) * 32 + lq * 8]);
        #pragma unroll
        for (int j = 0; j < 4; j++)
            bfr[j] = *reinterpret_cast<const s16x8*>(&Bs[(wn + j * 16 + lm) * 32 + lq * 8]);
        #pragma unroll
        for (int i = 0; i < 4; i++)
            #pragma unroll
            for (int j = 0; j < 4; j++)
                acc[i][j] = __builtin_amdgcn_mfma_f32_16x16x32_bf16(af[i], bfr[j], acc[i][j], 0, 0, 0);
        __syncthreads();
    }
    #pragma unroll
    for (int i = 0; i < 4; i++) {
        #pragma unroll
        for (int j = 0; j < 4; j++) {
            int col = n0 + wn + j * 16 + lm;
            if (col < N) {
                #pragma unroll
                for (int r = 0; r < 4; r++) {
                    int row = m0 + wm + i * 16 + lq * 4 + r;
                    float v = acc[i][j][r];
                    if (col < 2048) {
                        zbuf[(size_t)row * 2048 + col] = f2bf(v);
                    } else if (col < 4224) {
                        xbc[(size_t)row * 2176 + (col - 2048)] = f2bf(v);
                    } else {
                        float tt = v + dt_bias[col - 4224];
                        float sp = (tt > 20.f) ? tt : log1pf(expf(tt));
                        dtsp[(size_t)row * 32 + (col - 4224)] = sp;
                    }
                }
            }
        }
    }
}

// ---------------- GEMM2: out = yfin @ W_out^T + x (fp32 out) ----------------
__global__ __launch_bounds__(256)
void gemm_out_kernel(const u16* __restrict__ A, const u16* __restrict__ W,
                     float* __restrict__ C, const float* __restrict__ resid,
                     int M, int N, int K) {
    __shared__ __align__(16) u16 As[128 * 32];
    __shared__ __align__(16) u16 Bs[128 * 32];
    int t = threadIdx.x;
    int m0 = blockIdx.x * 128, n0 = blockIdx.y * 128;
    int wave = t >> 6, lane = t & 63;
    int wm = (wave >> 1) * 64, wn = (wave & 1) * 64;
    int lm = lane & 15, lq = lane >> 4;
    int srow = lane >> 2, scol = (lane & 3) * 8;
    f32x4 acc[4][4];
    #pragma unroll
    for (int i = 0; i < 4; i++)
        #pragma unroll
        for (int j = 0; j < 4; j++) acc[i][j] = (f32x4){0.f, 0.f, 0.f, 0.f};
    for (int k0 = 0; k0 < K; k0 += 32) {
        #pragma unroll
        for (int s = 0; s < 2; s++) {
            int ch = s * 4 + wave;
            int row = ch * 16 + srow;
            async_copy16(A + (size_t)(m0 + row) * K + k0 + scol, &As[ch * 512 + lane * 8]);
            async_copy16(W + (size_t)(n0 + row) * K + k0 + scol, &Bs[ch * 512 + lane * 8]);
        }
        __syncthreads();
        s16x8 af[4], bfr[4];
        #pragma unroll
        for (int i = 0; i < 4; i++)
            af[i] = *reinterpret_cast<const s16x8*>(&As[(wm + i * 16 + lm) * 32 + lq * 8]);
        #pragma unroll
        for (int j = 0; j < 4; j++)
            bfr[j] = *reinterpret_cast<const s16x8*>(&Bs[(wn + j * 16 + lm) * 32 + lq * 8]);
        #pragma unroll
        for (int i = 0; i < 4; i++)
            #pragma unroll
            for (int j = 0; j < 4; j++)
                acc[i][j] = __builtin_amdgcn_mfma_f32_16x16x32_bf16(af[i], bfr[j], acc[i][j], 0, 0, 0);
        __syncthreads();
    }
    #pragma unroll
    for (int i = 0; i < 4; i++)
        #pragma unroll
        for (int j = 0; j < 4; j++) {
            int col = n0 + wn + j * 16 + lm;
            #pragma unroll
            for (int r = 0; r < 4; r++) {
                int row = m0 + wm + i * 16 + lq * 4 + r;
                size_t off = (size_t)row * N + col;
                C[off] = acc[i][j][r] + resid[off];
            }
        }
}

// ---------------- depthwise causal conv (width 4) + bias + SiLU --------------
// Thread = (channel c, strip of 8 rows). Lanes -> consecutive c: all x loads /
// stores are coalesced 128B wave transactions; weights = one float4 + one float
// per thread (conv_w[c][0..3] contiguous). 11 row-loads -> 8 outputs (reuse).
__global__ __launch_bounds__(256)
void conv_kernel(const u16* __restrict__ xbc, const float* __restrict__ cw,
                 const float* __restrict__ cb, u16* __restrict__ xact) {
    int idx = blockIdx.x * 256 + threadIdx.x;
    if (idx >= 2 * 512 * 2176) return;
    int c = idx % 2176;
    int r = idx / 2176;          // 0..1023
    int lt = r & 511, b = r >> 9;
    int l0 = lt * 8;
    const u16* base = xbc + (size_t)b * 4096 * 2176 + c;
    float xv[11];
    #pragma unroll
    for (int i = 0; i < 11; i++) {
        int lk = l0 - 3 + i;
        xv[i] = (lk >= 0) ? bf2f(base[(size_t)lk * 2176]) : 0.f;
    }
    float4 w = *reinterpret_cast<const float4*>(cw + c * 4);
    float bias = cb[c];
    u16* ob = xact + (size_t)b * 4096 * 2176 + c;
    #pragma unroll
    for (int i = 0; i < 8; i++) {
        float a = bias + w.x * xv[i] + w.y * xv[i + 1] + w.z * xv[i + 2] + w.w * xv[i + 3];
        float s = a / (1.f + __expf(-a));
        ob[(size_t)(l0 + i) * 2176] = f2bf(s);
    }
}

// ====== chunked SSD scan: Q=64 chunks, units = (b,h,c) = 2*32*64 = 4096 ======
#define TS 72
__device__ __forceinline__ void mfma_quad(const u16* Pa, const u16* Qb,
                                          int mh, int nh, int lm, int lq,
                                          f32x4 acc[2][2]) {
    #pragma unroll
    for (int ks = 0; ks < 2; ks++) {
        s16x8 a[2], b[2];
        #pragma unroll
        for (int ti = 0; ti < 2; ti++)
            a[ti] = *reinterpret_cast<const s16x8*>(&Pa[(mh * 32 + ti * 16 + lm) * TS + ks * 32 + lq * 8]);
        #pragma unroll
        for (int tj = 0; tj < 2; tj++)
            b[tj] = *reinterpret_cast<const s16x8*>(&Qb[(nh * 32 + tj * 16 + lm) * TS + ks * 32 + lq * 8]);
        #pragma unroll
        for (int ti = 0; ti < 2; ti++)
            #pragma unroll
            for (int tj = 0; tj < 2; tj++)
                acc[ti][tj] = __builtin_amdgcn_mfma_f32_16x16x32_bf16(a[ti], b[tj], acc[ti][tj], 0, 0, 0);
    }
}

// Phase A: per unit, cumsum s_j, w_j = exp(s63-s_j)*dt_j; dH[p,n] = sum_j w_j x[j,p] B[j,n]
__global__ __launch_bounds__(256)
void chunk_dh_kernel(const u16* __restrict__ xact, const float* __restrict__ dtsp,
                     const float* __restrict__ A_log,
                     float* __restrict__ ssum, u16* __restrict__ dH) {
    int blk = blockIdx.x;
    int c = blk & 63, h = (blk >> 6) & 31, b = blk >> 11;
    __shared__ __align__(16) u16 Xw[64 * TS];
    __shared__ __align__(16) u16 Bt[64 * TS];
    __shared__ float sW[64];
    int t = threadIdx.x;
    int row0 = b * 4096 + c * 64;
    if (t < 64) {
        float dtv = dtsp[(size_t)(row0 + t) * 32 + h];
        float Ah = -__expf(A_log[h]);
        float s = dtv * Ah;
        #pragma unroll
        for (int o = 1; o < 64; o <<= 1) {
            float up = __shfl_up(s, o);
            if (t >= o) s += up;
        }
        float slast = __shfl(s, 63);
        sW[t] = __expf(slast - s) * dtv;
        ssum[(size_t)blk * 64 + t] = s;
    }
    __syncthreads();
    int j = t & 63, cg = (t >> 6) * 16;
    {
        float wj = sW[j];
        const u16* xr = xact + (size_t)(row0 + j) * 2176 + h * 64 + cg;
        u16x8 v0 = *reinterpret_cast<const u16x8*>(xr);
        u16x8 v1 = *reinterpret_cast<const u16x8*>(xr + 8);
        #pragma unroll
        for (int i = 0; i < 8; i++) Xw[(cg + i) * TS + j] = f2bf(bf2f(v0[i]) * wj);
        #pragma unroll
        for (int i = 0; i < 8; i++) Xw[(cg + 8 + i) * TS + j] = f2bf(bf2f(v1[i]) * wj);
        const u16* br = xact + (size_t)(row0 + j) * 2176 + 2048 + cg;
        u16x8 w0 = *reinterpret_cast<const u16x8*>(br);
        u16x8 w1 = *reinterpret_cast<const u16x8*>(br + 8);
        #pragma unroll
        for (int i = 0; i < 8; i++) Bt[(cg + i) * TS + j] = w0[i];
        #pragma unroll
        for (int i = 0; i < 8; i++) Bt[(cg + 8 + i) * TS + j] = w1[i];
    }
    __syncthreads();
    int wave = t >> 6, lane = t & 63, lm = lane & 15, lq = lane >> 4;
    int mh = wave >> 1, nh = wave & 1;
    f32x4 acc[2][2];
    #pragma unroll
    for (int i = 0; i < 2; i++)
        #pragma unroll
        for (int jj = 0; jj < 2; jj++) acc[i][jj] = (f32x4){0.f, 0.f, 0.f, 0.f};
    mfma_quad(Xw, Bt, mh, nh, lm, lq, acc);
    u16* out = dH + (size_t)blk * 4096;
    #pragma unroll
    for (int ti = 0; ti < 2; ti++)
        #pragma unroll
        for (int tj = 0; tj < 2; tj++)
            #pragma unroll
            for (int r = 0; r < 4; r++) {
                int p = mh * 32 + ti * 16 + lq * 4 + r;
                int n = nh * 32 + tj * 16 + lm;
                out[p * 64 + n] = f2bf(acc[ti][tj][r]);
            }
}

// Phase B: inter-chunk recurrence. grid (64 bh, 8 col-groups), 128 threads, 4 states each.
__global__ __launch_bounds__(128)
void chunk_scan_kernel(const u16* __restrict__ dH, const float* __restrict__ ssum,
                       u16* __restrict__ Hst) {
    int bh = blockIdx.x, g = blockIdx.y, t = threadIdx.x;
    int idx = g * 512 + t * 4;
    float H[4] = {0.f, 0.f, 0.f, 0.f};
    for (int c = 0; c < 64; c++) {
        size_t base = ((size_t)bh * 64 + c) * 4096 + idx;
        float lam = __expf(ssum[((size_t)bh * 64 + c) * 64 + 63]);
        u16x4 dh = *reinterpret_cast<const u16x4*>(dH + base);
        u16x4 hv;
        #pragma unroll
        for (int i = 0; i < 4; i++) hv[i] = f2bf(H[i]);
        *reinterpret_cast<u16x4*>(Hst + base) = hv;
        #pragma unroll
        for (int i = 0; i < 4; i++) H[i] = H[i] * lam + bf2f(dh[i]);
    }
}

// Phase C: per unit: G=C.B^T -> M (masked/weighted) ; Y = M@X + exp(s_i)*(C@H^T) + D*x
__global__ __launch_bounds__(256)
void chunk_out_kernel(const u16* __restrict__ xact, const float* __restrict__ dtsp,
                      const float* __restrict__ ssum, const u16* __restrict__ Hst,
                      const float* __restrict__ Dp, u16* __restrict__ yraw) {
    int blk = blockIdx.x;
    int c = blk & 63, h = (blk >> 6) & 31, b = blk >> 11;
    __shared__ __align__(16) u16 Ct[64 * TS];
    __shared__ __align__(16) u16 BM[64 * TS];
    __shared__ __align__(16) u16 Xt[64 * TS];
    __shared__ __align__(16) u16 Hs[64 * TS];
    __shared__ float sS[64], sDt[64], sE[64];
    int t = threadIdx.x;
    int row0 = b * 4096 + c * 64;
    if (t < 64) {
        float dtv = dtsp[(size_t)(row0 + t) * 32 + h];
        float s = ssum[(size_t)blk * 64 + t];
        sS[t] = s; sDt[t] = dtv; sE[t] = __expf(s);
    }
    int r2 = t >> 2, cg2 = (t & 3) * 16;
    {
        const u16* cr = xact + (size_t)(row0 + r2) * 2176 + 2112 + cg2;
        *reinterpret_cast<u16x8*>(&Ct[r2 * TS + cg2]) = *reinterpret_cast<const u16x8*>(cr);
        *reinterpret_cast<u16x8*>(&Ct[r2 * TS + cg2 + 8]) = *reinterpret_cast<const u16x8*>(cr + 8);
        const u16* br = xact + (size_t)(row0 + r2) * 2176 + 2048 + cg2;
        *reinterpret_cast<u16x8*>(&BM[r2 * TS + cg2]) = *reinterpret_cast<const u16x8*>(br);
        *reinterpret_cast<u16x8*>(&BM[r2 * TS + cg2 + 8]) = *reinterpret_cast<const u16x8*>(br + 8);
        const u16* hr = Hst + (size_t)blk * 4096 + r2 * 64 + cg2;
        *reinterpret_cast<u16x8*>(&Hs[r2 * TS + cg2]) = *reinterpret_cast<const u16x8*>(hr);
        *reinterpret_cast<u16x8*>(&Hs[r2 * TS + cg2 + 8]) = *reinterpret_cast<const u16x8*>(hr + 8);
    }
    int j = t & 63, cg = (t >> 6) * 16;
    {
        const u16* xr = xact + (size_t)(row0 + j) * 2176 + h * 64 + cg;
        u16x8 v0 = *reinterpret_cast<const u16x8*>(xr);
        u16x8 v1 = *reinterpret_cast<const u16x8*>(xr + 8);
        #pragma unroll
        for (int i = 0; i < 8; i++) Xt[(cg + i) * TS + j] = v0[i];
        #pragma unroll
        for (int i = 0; i < 8; i++) Xt[(cg + 8 + i) * TS + j] = v1[i];
    }
    __syncthreads();
    int wave = t >> 6, lane = t & 63, lm = lane & 15, lq = lane >> 4;
    int mh = wave >> 1, nh = wave & 1;
    f32x4 g1[2][2], y2[2][2], y3[2][2];
    #pragma unroll
    for (int i = 0; i < 2; i++)
        #pragma unroll
        for (int jj = 0; jj < 2; jj++) {
            g1[i][jj] = (f32x4){0.f, 0.f, 0.f, 0.f};
            y2[i][jj] = (f32x4){0.f, 0.f, 0.f, 0.f};
            y3[i][jj] = (f32x4){0.f, 0.f, 0.f, 0.f};
        }
    mfma_quad(Ct, BM, mh, nh, lm, lq, g1);
    __syncthreads();
    #pragma unroll
    for (int ti = 0; ti < 2; ti++)
        #pragma unroll
        for (int tj = 0; tj < 2; tj++) {
            int j_ = nh * 32 + tj * 16 + lm;
            float sj = sS[j_], dtj = sDt[j_];
            #pragma unroll
            for (int r = 0; r < 4; r++) {
                int ii = mh * 32 + ti * 16 + lq * 4 + r;
                float v = g1[ti][tj][r] * __expf(sS[ii] - sj) * dtj;
                v = (j_ <= ii) ? v : 0.f;
                BM[ii * TS + j_] = f2bf(v);
            }
        }
    __syncthreads();
    mfma_quad(BM, Xt, mh, nh, lm, lq, y2);
    mfma_quad(Ct, Hs, mh, nh, lm, lq, y3);
    float Dh = Dp[h];
    #pragma unroll
    for (int ti = 0; ti < 2; ti++)
        #pragma unroll
        for (int tj = 0; tj < 2; tj++)
            #pragma unroll
            for (int r = 0; r < 4; r++) {
                int ii = mh * 32 + ti * 16 + lq * 4 + r;
                int p = nh * 32 + tj * 16 + lm;
                float xv = bf2f(Xt[p * TS + ii]);
                float y = y2[ti][tj][r] + sE[ii] * y3[ti][tj][r] + Dh * xv;
                yraw[(size_t)(row0 + ii) * 2048 + h * 64 + p] = f2bf(y);
            }
}

// ---------------- gate (y * silu(z)) + RMSNorm * norm_w ----------------
__global__ __launch_bounds__(256)
void gate_kernel(const u16* __restrict__ yraw, const u16* __restrict__ zbuf,
                 const float* __restrict__ nw, u16* __restrict__ yfin) {
    int row = blockIdx.x, t = threadIdx.x;
    u16x8 yv = *reinterpret_cast<const u16x8*>(yraw + (size_t)row * 2048 + t * 8);
    u16x8 zv = *reinterpret_cast<const u16x8*>(zbuf + (size_t)row * 2048 + t * 8);
    float g[8]; float sq = 0.f;
    #pragma unroll
    for (int i = 0; i < 8; i++) {
        float z = bf2f(zv[i]);
        float gg = bf2f(yv[i]) * (z / (1.f + expf(-z)));
        g[i] = gg; sq += gg * gg;
    }
    #pragma unroll
    for (int o = 32; o; o >>= 1) sq += __shfl_down(sq, o);
    __shared__ float rq[4];
    int lane = t & 63, wv = t >> 6;
    if (!lane) rq[wv] = sq;
    __syncthreads();
    sq = rq[0] + rq[1] + rq[2] + rq[3];
    float scale = rsqrtf(sq * (1.f / 2048.f) + 1e-5f);
    float4 n0 = *reinterpret_cast<const float4*>(nw + t * 8);
    float4 n1 = *reinterpret_cast<const float4*>(nw + t * 8 + 4);
    float nf[8] = {n0.x, n0.y, n0.z, n0.w, n1.x, n1.y, n1.z, n1.w};
    u16x8 o8;
    #pragma unroll
    for (int i = 0; i < 8; i++) o8[i] = f2bf(g[i] * scale * nf[i]);
    *reinterpret_cast<u16x8*>(yfin + (size_t)row * 2048 + t * 8) = o8;
}

extern "C" void kernel_launch(void* const* d_in, const int* in_sizes, int n_in,
                              void* d_out, int out_size, void* d_ws, size_t ws_size,
                              hipStream_t stream) {
    const float* x       = (const float*)d_in[0];
    const float* ln_w    = (const float*)d_in[1];
    const float* ln_b    = (const float*)d_in[2];
    const float* W_in    = (const float*)d_in[3];
    const float* conv_w  = (const float*)d_in[4];
    const float* conv_b  = (const float*)d_in[5];
    const float* dt_bias = (const float*)d_in[6];
    const float* A_log   = (const float*)d_in[7];
    const float* Dp      = (const float*)d_in[8];
    const float* norm_w  = (const float*)d_in[9];
    const float* W_out   = (const float*)d_in[10];
    float* out = (float*)d_out;

    char* ws = (char*)d_ws;
    u16*  zbuf    = (u16*)(ws + 0);               // 33,554,432  [gemm1 -> gate]
    u16*  xbc     = (u16*)(ws + 33554432);        // 35,651,584  [gemm1 -> conv]
    u16*  Hst     = (u16*)(ws + 33554432);        // 33,554,432  [phaseB -> phaseC] overlays xbc
    u16*  xact    = (u16*)(ws + 69206016);        // 35,651,584  [conv -> phaseC]
    u16*  yfin    = xact;                         // [gate -> gemm2] overlays xact
    u16*  u_buf   = (u16*)(ws + 104857600);       // 16,777,216  [ln -> gemm1]
    float* ssum   = (float*)(ws + 104857600);     //  1,048,576  [phaseA -> phaseC] overlays u_buf
    float* dtsp   = (float*)(ws + 121634816);     //  1,048,576  [gemm1 -> phaseC]
    u16*  dH      = (u16*)(ws + 122683392);       // 33,554,432  [phaseA -> phaseB]
    u16*  yraw    = (u16*)(ws + 122683392);       // [phaseC -> gate] overlays dH
    u16*  w_in_bf = (u16*)(ws + 156237824);       //  8,716,288
    u16*  w_out_bf= (u16*)(ws + 164954112);       //  4,194,304

    cvt_kernel<<<(1089536 + 524288 + 255) / 256, 256, 0, stream>>>(
        W_in, w_in_bf, 1089536, W_out, w_out_bf, 524288);

    ln_kernel<<<8192, 256, 0, stream>>>(x, ln_w, ln_b, u_buf);

    dim3 g1(64, 34);
    gemm_in_kernel<<<g1, 256, 0, stream>>>(u_buf, w_in_bf, zbuf, xbc, dtsp, dt_bias,
                                           8192, 4256, 1024);

    conv_kernel<<<(2 * 512 * 2176 + 255) / 256, 256, 0, stream>>>(xbc, conv_w, conv_b, xact);

    chunk_dh_kernel<<<4096, 256, 0, stream>>>(xact, dtsp, A_log, ssum, dH);
    chunk_scan_kernel<<<dim3(64, 8), 128, 0, stream>>>(dH, ssum, Hst);
    chunk_out_kernel<<<4096, 256, 0, stream>>>(xact, dtsp, ssum, Hst, Dp, yraw);

    gate_kernel<<<8192, 256, 0, stream>>>(yraw, zbuf, norm_w, yfin);

    dim3 g2(64, 8);
    gemm_out_kernel<<<g2, 256, 0, stream>>>(yfin, w_out_bf, out, x, 8192, 1024, 2048);
}

// Round 8
// 379.991 us; speedup vs baseline: 1.2724x; 1.0116x over previous
//
#include <hip/hip_runtime.h>
#include <math.h>

typedef unsigned short u16;
typedef __attribute__((ext_vector_type(4))) float f32x4;
typedef __attribute__((ext_vector_type(8))) short s16x8;
typedef __attribute__((ext_vector_type(8))) unsigned short u16x8;
typedef __attribute__((ext_vector_type(4))) unsigned short u16x4;

__device__ __forceinline__ float bf2f(u16 v) {
    union { unsigned u; float f; } c; c.u = ((unsigned)v) << 16; return c.f;
}
__device__ __forceinline__ u16 f2bf(float f) {
    union { float f; unsigned u; } c; c.f = f;
    unsigned x = c.u;
    unsigned r = (x + 0x7fffu + ((x >> 16) & 1u)) >> 16;  // RNE
    return (u16)r;
}

// async HBM -> LDS, 16 B per lane. LDS dest is wave-uniform base + lane*16.
__device__ __forceinline__ void async_copy16(const u16* g, u16* l) {
    __builtin_amdgcn_global_load_lds(
        (const __attribute__((address_space(1))) unsigned int*)g,
        (__attribute__((address_space(3))) unsigned int*)l, 16, 0, 0);
}

// ---------------- fp32 -> bf16 weight conversion (both weights, one launch) --
__global__ __launch_bounds__(256)
void cvt_kernel(const float* __restrict__ in_a, u16* __restrict__ out_a, int n4a,
                const float* __restrict__ in_b, u16* __restrict__ out_b, int n4b) {
    int i = blockIdx.x * 256 + threadIdx.x;
    const float* in; u16* out; int k;
    if (i < n4a) { in = in_a; out = out_a; k = i; }
    else if (i < n4a + n4b) { in = in_b; out = out_b; k = i - n4a; }
    else return;
    float4 v = reinterpret_cast<const float4*>(in)[k];
    u16x4 o;
    o[0] = f2bf(v.x); o[1] = f2bf(v.y); o[2] = f2bf(v.z); o[3] = f2bf(v.w);
    reinterpret_cast<u16x4*>(out)[k] = o;
}

// ---------------- LayerNorm: x fp32 (8192 x 1024) -> u bf16 ----------------
__global__ __launch_bounds__(256)
void ln_kernel(const float* __restrict__ x, const float* __restrict__ w,
               const float* __restrict__ b, u16* __restrict__ u) {
    int row = blockIdx.x, t = threadIdx.x;
    const float* xr = x + (size_t)row * 1024;
    float4 xv = *reinterpret_cast<const float4*>(xr + t * 4);
    float f[4] = {xv.x, xv.y, xv.z, xv.w};
    float s = 0.f, sq = 0.f;
    #pragma unroll
    for (int i = 0; i < 4; i++) { s += f[i]; sq += f[i] * f[i]; }
    #pragma unroll
    for (int o = 32; o; o >>= 1) { s += __shfl_down(s, o); sq += __shfl_down(sq, o); }
    __shared__ float rs[4], rq[4];
    int lane = t & 63, wv = t >> 6;
    if (!lane) { rs[wv] = s; rq[wv] = sq; }
    __syncthreads();
    s = rs[0] + rs[1] + rs[2] + rs[3];
    sq = rq[0] + rq[1] + rq[2] + rq[3];
    float mu = s * (1.f / 1024.f);
    float var = sq * (1.f / 1024.f) - mu * mu;
    float rstd = rsqrtf(var + 1e-5f);
    float4 wv4 = *reinterpret_cast<const float4*>(w + t * 4);
    float4 bv4 = *reinterpret_cast<const float4*>(b + t * 4);
    float wf[4] = {wv4.x, wv4.y, wv4.z, wv4.w};
    float bf[4] = {bv4.x, bv4.y, bv4.z, bv4.w};
    u16x4 o4;
    #pragma unroll
    for (int i = 0; i < 4; i++)
        o4[i] = f2bf((f[i] - mu) * rstd * wf[i] + bf[i]);
    *reinterpret_cast<u16x4*>(u + (size_t)row * 1024 + t * 4) = o4;
}

// ---------------- GEMM1: zxbcdt = u @ W_in^T, split epilogue ----------------
// m97 structure: BK=32, global_load_lds 16B staging. launch_bounds(256,4):
// 4 blocks/CU (16 waves x 128 regs = full VGPR pool) to hide barrier drains.
__global__ __launch_bounds__(256, 4)
void gemm_in_kernel(const u16* __restrict__ A, const u16* __restrict__ W,
                    u16* __restrict__ zbuf, u16* __restrict__ xbc,
                    float* __restrict__ dtsp, const float* __restrict__ dt_bias,
                    int M, int N, int K) {
    __shared__ __align__(16) u16 As[128 * 32];
    __shared__ __align__(16) u16 Bs[128 * 32];
    int t = threadIdx.x;
    int m0 = blockIdx.x * 128, n0 = blockIdx.y * 128;
    int wave = t >> 6, lane = t & 63;
    int wm = (wave >> 1) * 64, wn = (wave & 1) * 64;
    int lm = lane & 15, lq = lane >> 4;
    int srow = lane >> 2, scol = (lane & 3) * 8;   // 4 lanes cover one 32-col row
    f32x4 acc[4][4];
    #pragma unroll
    for (int i = 0; i < 4; i++)
        #pragma unroll
        for (int j = 0; j < 4; j++) acc[i][j] = (f32x4){0.f, 0.f, 0.f, 0.f};

    for (int k0 = 0; k0 < K; k0 += 32) {
        #pragma unroll
        for (int s = 0; s < 2; s++) {
            int ch = s * 4 + wave;               // 8 chunks of 16 rows
            int row = ch * 16 + srow;
            async_copy16(A + (size_t)(m0 + row) * K + k0 + scol, &As[ch * 512 + lane * 8]);
            int rn = n0 + row;
            if (rn < N)
                async_copy16(W + (size_t)rn * K + k0 + scol, &Bs[ch * 512 + lane * 8]);
        }
        __syncthreads();
        s16x8 af[4], bfr[4];
        #pragma unroll
        for (int i = 0; i < 4; i++)
            af[i] = *reinterpret_cast<const s16x8*>(&As[(wm + i * 16 + lm) * 32 + lq * 8]);
        #pragma unroll
        for (int j = 0; j < 4; j++)
            bfr[j] = *reinterpret_cast<const s16x8*>(&Bs[(wn + j * 16 + lm) * 32 + lq * 8]);
        #pragma unroll
        for (int i = 0; i < 4; i++)
            #pragma unroll
            for (int j = 0; j < 4; j++)
                acc[i][j] = __builtin_amdgcn_mfma_f32_16x16x32_bf16(af[i], bfr[j], acc[i][j], 0, 0, 0);
        __syncthreads();
    }
    #pragma unroll
    for (int i = 0; i < 4; i++) {
        #pragma unroll
        for (int j = 0; j < 4; j++) {
            int col = n0 + wn + j * 16 + lm;
            if (col < N) {
                #pragma unroll
                for (int r = 0; r < 4; r++) {
                    int row = m0 + wm + i * 16 + lq * 4 + r;
                    float v = acc[i][j][r];
                    if (col < 2048) {
                        zbuf[(size_t)row * 2048 + col] = f2bf(v);
                    } else if (col < 4224) {
                        xbc[(size_t)row * 2176 + (col - 2048)] = f2bf(v);
                    } else {
                        float tt = v + dt_bias[col - 4224];
                        float sp = (tt > 20.f) ? tt : log1pf(expf(tt));
                        dtsp[(size_t)row * 32 + (col - 4224)] = sp;
                    }
                }
            }
        }
    }
}

// ---------------- GEMM2: out = yfin @ W_out^T + x (fp32 out) ----------------
__global__ __launch_bounds__(256, 4)
void gemm_out_kernel(const u16* __restrict__ A, const u16* __restrict__ W,
                     float* __restrict__ C, const float* __restrict__ resid,
                     int M, int N, int K) {
    __shared__ __align__(16) u16 As[128 * 32];
    __shared__ __align__(16) u16 Bs[128 * 32];
    int t = threadIdx.x;
    int m0 = blockIdx.x * 128, n0 = blockIdx.y * 128;
    int wave = t >> 6, lane = t & 63;
    int wm = (wave >> 1) * 64, wn = (wave & 1) * 64;
    int lm = lane & 15, lq = lane >> 4;
    int srow = lane >> 2, scol = (lane & 3) * 8;
    f32x4 acc[4][4];
    #pragma unroll
    for (int i = 0; i < 4; i++)
        #pragma unroll
        for (int j = 0; j < 4; j++) acc[i][j] = (f32x4){0.f, 0.f, 0.f, 0.f};
    for (int k0 = 0; k0 < K; k0 += 32) {
        #pragma unroll
        for (int s = 0; s < 2; s++) {
            int ch = s * 4 + wave;
            int row = ch * 16 + srow;
            async_copy16(A + (size_t)(m0 + row) * K + k0 + scol, &As[ch * 512 + lane * 8]);
            async_copy16(W + (size_t)(n0 + row) * K + k0 + scol, &Bs[ch * 512 + lane * 8]);
        }
        __syncthreads();
        s16x8 af[4], bfr[4];
        #pragma unroll
        for (int i = 0; i < 4; i++)
            af[i] = *reinterpret_cast<const s16x8*>(&As[(wm + i * 16 + lm) * 32 + lq * 8]);
        #pragma unroll
        for (int j = 0; j < 4; j++)
            bfr[j] = *reinterpret_cast<const s16x8*>(&Bs[(wn + j * 16 + lm) * 32 + lq * 8]);
        #pragma unroll
        for (int i = 0; i < 4; i++)
            #pragma unroll
            for (int j = 0; j < 4; j++)
                acc[i][j] = __builtin_amdgcn_mfma_f32_16x16x32_bf16(af[i], bfr[j], acc[i][j], 0, 0, 0);
        __syncthreads();
    }
    #pragma unroll
    for (int i = 0; i < 4; i++)
        #pragma unroll
        for (int j = 0; j < 4; j++) {
            int col = n0 + wn + j * 16 + lm;
            #pragma unroll
            for (int r = 0; r < 4; r++) {
                int row = m0 + wm + i * 16 + lq * 4 + r;
                size_t off = (size_t)row * N + col;
                C[off] = acc[i][j][r] + resid[off];
            }
        }
}

// ---------------- depthwise causal conv (width 4) + bias + SiLU --------------
// Thread = (channel c, strip of 8 rows). Lanes -> consecutive c: coalesced.
__global__ __launch_bounds__(256)
void conv_kernel(const u16* __restrict__ xbc, const float* __restrict__ cw,
                 const float* __restrict__ cb, u16* __restrict__ xact) {
    int idx = blockIdx.x * 256 + threadIdx.x;
    if (idx >= 2 * 512 * 2176) return;
    int c = idx % 2176;
    int r = idx / 2176;          // 0..1023
    int lt = r & 511, b = r >> 9;
    int l0 = lt * 8;
    const u16* base = xbc + (size_t)b * 4096 * 2176 + c;
    float xv[11];
    #pragma unroll
    for (int i = 0; i < 11; i++) {
        int lk = l0 - 3 + i;
        xv[i] = (lk >= 0) ? bf2f(base[(size_t)lk * 2176]) : 0.f;
    }
    float4 w = *reinterpret_cast<const float4*>(cw + c * 4);
    float bias = cb[c];
    u16* ob = xact + (size_t)b * 4096 * 2176 + c;
    #pragma unroll
    for (int i = 0; i < 8; i++) {
        float a = bias + w.x * xv[i] + w.y * xv[i + 1] + w.z * xv[i + 2] + w.w * xv[i + 3];
        float s = a / (1.f + __expf(-a));
        ob[(size_t)(l0 + i) * 2176] = f2bf(s);
    }
}

// ====== chunked SSD scan: Q=64 chunks, units = (b,h,c) = 2*32*64 = 4096 ======
#define TS 72
__device__ __forceinline__ void mfma_quad(const u16* Pa, const u16* Qb,
                                          int mh, int nh, int lm, int lq,
                                          f32x4 acc[2][2]) {
    #pragma unroll
    for (int ks = 0; ks < 2; ks++) {
        s16x8 a[2], b[2];
        #pragma unroll
        for (int ti = 0; ti < 2; ti++)
            a[ti] = *reinterpret_cast<const s16x8*>(&Pa[(mh * 32 + ti * 16 + lm) * TS + ks * 32 + lq * 8]);
        #pragma unroll
        for (int tj = 0; tj < 2; tj++)
            b[tj] = *reinterpret_cast<const s16x8*>(&Qb[(nh * 32 + tj * 16 + lm) * TS + ks * 32 + lq * 8]);
        #pragma unroll
        for (int ti = 0; ti < 2; ti++)
            #pragma unroll
            for (int tj = 0; tj < 2; tj++)
                acc[ti][tj] = __builtin_amdgcn_mfma_f32_16x16x32_bf16(a[ti], b[tj], acc[ti][tj], 0, 0, 0);
    }
}

// Phase A: per unit, cumsum s_j, w_j = exp(s63-s_j)*dt_j; dH[p,n] = sum_j w_j x[j,p] B[j,n]
__global__ __launch_bounds__(256)
void chunk_dh_kernel(const u16* __restrict__ xact, const float* __restrict__ dtsp,
                     const float* __restrict__ A_log,
                     float* __restrict__ ssum, u16* __restrict__ dH) {
    int blk = blockIdx.x;
    int c = blk & 63, h = (blk >> 6) & 31, b = blk >> 11;
    __shared__ __align__(16) u16 Xw[64 * TS];
    __shared__ __align__(16) u16 Bt[64 * TS];
    __shared__ float sW[64];
    int t = threadIdx.x;
    int row0 = b * 4096 + c * 64;
    if (t < 64) {
        float dtv = dtsp[(size_t)(row0 + t) * 32 + h];
        float Ah = -__expf(A_log[h]);
        float s = dtv * Ah;
        #pragma unroll
        for (int o = 1; o < 64; o <<= 1) {
            float up = __shfl_up(s, o);
            if (t >= o) s += up;
        }
        float slast = __shfl(s, 63);
        sW[t] = __expf(slast - s) * dtv;
        ssum[(size_t)blk * 64 + t] = s;
    }
    __syncthreads();
    int j = t & 63, cg = (t >> 6) * 16;
    {
        float wj = sW[j];
        const u16* xr = xact + (size_t)(row0 + j) * 2176 + h * 64 + cg;
        u16x8 v0 = *reinterpret_cast<const u16x8*>(xr);
        u16x8 v1 = *reinterpret_cast<const u16x8*>(xr + 8);
        #pragma unroll
        for (int i = 0; i < 8; i++) Xw[(cg + i) * TS + j] = f2bf(bf2f(v0[i]) * wj);
        #pragma unroll
        for (int i = 0; i < 8; i++) Xw[(cg + 8 + i) * TS + j] = f2bf(bf2f(v1[i]) * wj);
        const u16* br = xact + (size_t)(row0 + j) * 2176 + 2048 + cg;
        u16x8 w0 = *reinterpret_cast<const u16x8*>(br);
        u16x8 w1 = *reinterpret_cast<const u16x8*>(br + 8);
        #pragma unroll
        for (int i = 0; i < 8; i++) Bt[(cg + i) * TS + j] = w0[i];
        #pragma unroll
        for (int i = 0; i < 8; i++) Bt[(cg + 8 + i) * TS + j] = w1[i];
    }
    __syncthreads();
    int wave = t >> 6, lane = t & 63, lm = lane & 15, lq = lane >> 4;
    int mh = wave >> 1, nh = wave & 1;
    f32x4 acc[2][2];
    #pragma unroll
    for (int i = 0; i < 2; i++)
        #pragma unroll
        for (int jj = 0; jj < 2; jj++) acc[i][jj] = (f32x4){0.f, 0.f, 0.f, 0.f};
    mfma_quad(Xw, Bt, mh, nh, lm, lq, acc);
    u16* out = dH + (size_t)blk * 4096;
    #pragma unroll
    for (int ti = 0; ti < 2; ti++)
        #pragma unroll
        for (int tj = 0; tj < 2; tj++)
            #pragma unroll
            for (int r = 0; r < 4; r++) {
                int p = mh * 32 + ti * 16 + lq * 4 + r;
                int n = nh * 32 + tj * 16 + lm;
                out[p * 64 + n] = f2bf(acc[ti][tj][r]);
            }
}

// Phase B: inter-chunk recurrence; lam table precomputed once in LDS.
__global__ __launch_bounds__(128)
void chunk_scan_kernel(const u16* __restrict__ dH, const float* __restrict__ ssum,
                       u16* __restrict__ Hst) {
    int bh = blockIdx.x, g = blockIdx.y, t = threadIdx.x;
    __shared__ float sLam[64];
    if (t < 64)
        sLam[t] = __expf(ssum[((size_t)bh * 64 + t) * 64 + 63]);
    __syncthreads();
    int idx = g * 512 + t * 4;
    float H[4] = {0.f, 0.f, 0.f, 0.f};
    #pragma unroll 4
    for (int c = 0; c < 64; c++) {
        size_t base = ((size_t)bh * 64 + c) * 4096 + idx;
        float lam = sLam[c];
        u16x4 dh = *reinterpret_cast<const u16x4*>(dH + base);
        u16x4 hv;
        #pragma unroll
        for (int i = 0; i < 4; i++) hv[i] = f2bf(H[i]);
        *reinterpret_cast<u16x4*>(Hst + base) = hv;
        #pragma unroll
        for (int i = 0; i < 4; i++) H[i] = H[i] * lam + bf2f(dh[i]);
    }
}

// Phase C: per unit: G=C.B^T -> M (masked/weighted) ; Y = M@X + exp(s_i)*(C@H^T) + D*x
__global__ __launch_bounds__(256)
void chunk_out_kernel(const u16* __restrict__ xact, const float* __restrict__ dtsp,
                      const float* __restrict__ ssum, const u16* __restrict__ Hst,
                      const float* __restrict__ Dp, u16* __restrict__ yraw) {
    int blk = blockIdx.x;
    int c = blk & 63, h = (blk >> 6) & 31, b = blk >> 11;
    __shared__ __align__(16) u16 Ct[64 * TS];
    __shared__ __align__(16) u16 BM[64 * TS];
    __shared__ __align__(16) u16 Xt[64 * TS];
    __shared__ __align__(16) u16 Hs[64 * TS];
    __shared__ float sS[64], sDt[64], sE[64];
    int t = threadIdx.x;
    int row0 = b * 4096 + c * 64;
    if (t < 64) {
        float dtv = dtsp[(size_t)(row0 + t) * 32 + h];
        float s = ssum[(size_t)blk * 64 + t];
        sS[t] = s; sDt[t] = dtv; sE[t] = __expf(s);
    }
    int r2 = t >> 2, cg2 = (t & 3) * 16;
    {
        const u16* cr = xact + (size_t)(row0 + r2) * 2176 + 2112 + cg2;
        *reinterpret_cast<u16x8*>(&Ct[r2 * TS + cg2]) = *reinterpret_cast<const u16x8*>(cr);
        *reinterpret_cast<u16x8*>(&Ct[r2 * TS + cg2 + 8]) = *reinterpret_cast<const u16x8*>(cr + 8);
        const u16* br = xact + (size_t)(row0 + r2) * 2176 + 2048 + cg2;
        *reinterpret_cast<u16x8*>(&BM[r2 * TS + cg2]) = *reinterpret_cast<const u16x8*>(br);
        *reinterpret_cast<u16x8*>(&BM[r2 * TS + cg2 + 8]) = *reinterpret_cast<const u16x8*>(br + 8);
        const u16* hr = Hst + (size_t)blk * 4096 + r2 * 64 + cg2;
        *reinterpret_cast<u16x8*>(&Hs[r2 * TS + cg2]) = *reinterpret_cast<const u16x8*>(hr);
        *reinterpret_cast<u16x8*>(&Hs[r2 * TS + cg2 + 8]) = *reinterpret_cast<const u16x8*>(hr + 8);
    }
    int j = t & 63, cg = (t >> 6) * 16;
    {
        const u16* xr = xact + (size_t)(row0 + j) * 2176 + h * 64 + cg;
        u16x8 v0 = *reinterpret_cast<const u16x8*>(xr);
        u16x8 v1 = *reinterpret_cast<const u16x8*>(xr + 8);
        #pragma unroll
        for (int i = 0; i < 8; i++) Xt[(cg + i) * TS + j] = v0[i];
        #pragma unroll
        for (int i = 0; i < 8; i++) Xt[(cg + 8 + i) * TS + j] = v1[i];
    }
    __syncthreads();
    int wave = t >> 6, lane = t & 63, lm = lane & 15, lq = lane >> 4;
    int mh = wave >> 1, nh = wave & 1;
    f32x4 g1[2][2], y2[2][2], y3[2][2];
    #pragma unroll
    for (int i = 0; i < 2; i++)
        #pragma unroll
        for (int jj = 0; jj < 2; jj++) {
            g1[i][jj] = (f32x4){0.f, 0.f, 0.f, 0.f};
            y2[i][jj] = (f32x4){0.f, 0.f, 0.f, 0.f};
            y3[i][jj] = (f32x4){0.f, 0.f, 0.f, 0.f};
        }
    mfma_quad(Ct, BM, mh, nh, lm, lq, g1);
    __syncthreads();
    #pragma unroll
    for (int ti = 0; ti < 2; ti++)
        #pragma unroll
        for (int tj = 0; tj < 2; tj++) {
            int j_ = nh * 32 + tj * 16 + lm;
            float sj = sS[j_], dtj = sDt[j_];
            #pragma unroll
            for (int r = 0; r < 4; r++) {
                int ii = mh * 32 + ti * 16 + lq * 4 + r;
                float v = g1[ti][tj][r] * __expf(sS[ii] - sj) * dtj;
                v = (j_ <= ii) ? v : 0.f;
                BM[ii * TS + j_] = f2bf(v);
            }
        }
    __syncthreads();
    mfma_quad(BM, Xt, mh, nh, lm, lq, y2);
    mfma_quad(Ct, Hs, mh, nh, lm, lq, y3);
    float Dh = Dp[h];
    #pragma unroll
    for (int ti = 0; ti < 2; ti++)
        #pragma unroll
        for (int tj = 0; tj < 2; tj++)
            #pragma unroll
            for (int r = 0; r < 4; r++) {
                int ii = mh * 32 + ti * 16 + lq * 4 + r;
                int p = nh * 32 + tj * 16 + lm;
                float xv = bf2f(Xt[p * TS + ii]);
                float y = y2[ti][tj][r] + sE[ii] * y3[ti][tj][r] + Dh * xv;
                yraw[(size_t)(row0 + ii) * 2048 + h * 64 + p] = f2bf(y);
            }
}

// ---------------- gate (y * silu(z)) + RMSNorm * norm_w ----------------
__global__ __launch_bounds__(256)
void gate_kernel(const u16* __restrict__ yraw, const u16* __restrict__ zbuf,
                 const float* __restrict__ nw, u16* __restrict__ yfin) {
    int row = blockIdx.x, t = threadIdx.x;
    u16x8 yv = *reinterpret_cast<const u16x8*>(yraw + (size_t)row * 2048 + t * 8);
    u16x8 zv = *reinterpret_cast<const u16x8*>(zbuf + (size_t)row * 2048 + t * 8);
    float g[8]; float sq = 0.f;
    #pragma unroll
    for (int i = 0; i < 8; i++) {
        float z = bf2f(zv[i]);
        float gg = bf2f(yv[i]) * (z / (1.f + expf(-z)));
        g[i] = gg; sq += gg * gg;
    }
    #pragma unroll
    for (int o = 32; o; o >>= 1) sq += __shfl_down(sq, o);
    __shared__ float rq[4];
    int lane = t & 63, wv = t >> 6;
    if (!lane) rq[wv] = sq;
    __syncthreads();
    sq = rq[0] + rq[1] + rq[2] + rq[3];
    float scale = rsqrtf(sq * (1.f / 2048.f) + 1e-5f);
    float4 n0 = *reinterpret_cast<const float4*>(nw + t * 8);
    float4 n1 = *reinterpret_cast<const float4*>(nw + t * 8 + 4);
    float nf[8] = {n0.x, n0.y, n0.z, n0.w, n1.x, n1.y, n1.z, n1.w};
    u16x8 o8;
    #pragma unroll
    for (int i = 0; i < 8; i++) o8[i] = f2bf(g[i] * scale * nf[i]);
    *reinterpret_cast<u16x8*>(yfin + (size_t)row * 2048 + t * 8) = o8;
}

extern "C" void kernel_launch(void* const* d_in, const int* in_sizes, int n_in,
                              void* d_out, int out_size, void* d_ws, size_t ws_size,
                              hipStream_t stream) {
    const float* x       = (const float*)d_in[0];
    const float* ln_w    = (const float*)d_in[1];
    const float* ln_b    = (const float*)d_in[2];
    const float* W_in    = (const float*)d_in[3];
    const float* conv_w  = (const float*)d_in[4];
    const float* conv_b  = (const float*)d_in[5];
    const float* dt_bias = (const float*)d_in[6];
    const float* A_log   = (const float*)d_in[7];
    const float* Dp      = (const float*)d_in[8];
    const float* norm_w  = (const float*)d_in[9];
    const float* W_out   = (const float*)d_in[10];
    float* out = (float*)d_out;

    char* ws = (char*)d_ws;
    u16*  zbuf    = (u16*)(ws + 0);               // 33,554,432  [gemm1 -> gate]
    u16*  xbc     = (u16*)(ws + 33554432);        // 35,651,584  [gemm1 -> conv]
    u16*  Hst     = (u16*)(ws + 33554432);        // 33,554,432  [phaseB -> phaseC] overlays xbc
    u16*  xact    = (u16*)(ws + 69206016);        // 35,651,584  [conv -> phaseC]
    u16*  yfin    = xact;                         // [gate -> gemm2] overlays xact
    u16*  u_buf   = (u16*)(ws + 104857600);       // 16,777,216  [ln -> gemm1]
    float* ssum   = (float*)(ws + 104857600);     //  1,048,576  [phaseA -> phaseC] overlays u_buf
    float* dtsp   = (float*)(ws + 121634816);     //  1,048,576  [gemm1 -> phaseC]
    u16*  dH      = (u16*)(ws + 122683392);       // 33,554,432  [phaseA -> phaseB]
    u16*  yraw    = (u16*)(ws + 122683392);       // [phaseC -> gate] overlays dH
    u16*  w_in_bf = (u16*)(ws + 156237824);       //  8,716,288
    u16*  w_out_bf= (u16*)(ws + 164954112);       //  4,194,304

    cvt_kernel<<<(1089536 + 524288 + 255) / 256, 256, 0, stream>>>(
        W_in, w_in_bf, 1089536, W_out, w_out_bf, 524288);

    ln_kernel<<<8192, 256, 0, stream>>>(x, ln_w, ln_b, u_buf);

    dim3 g1(64, 34);
    gemm_in_kernel<<<g1, 256, 0, stream>>>(u_buf, w_in_bf, zbuf, xbc, dtsp, dt_bias,
                                           8192, 4256, 1024);

    conv_kernel<<<(2 * 512 * 2176 + 255) / 256, 256, 0, stream>>>(xbc, conv_w, conv_b, xact);

    chunk_dh_kernel<<<4096, 256, 0, stream>>>(xact, dtsp, A_log, ssum, dH);
    chunk_scan_kernel<<<dim3(64, 8), 128, 0, stream>>>(dH, ssum, Hst);
    chunk_out_kernel<<<4096, 256, 0, stream>>>(xact, dtsp, ssum, Hst, Dp, yraw);

    gate_kernel<<<8192, 256, 0, stream>>>(yraw, zbuf, norm_w, yfin);

    dim3 g2(64, 8);
    gemm_out_kernel<<<g2, 256, 0, stream>>>(yfin, w_out_bf, out, x, 8192, 1024, 2048);
}